// Round 5
// baseline (102.470 us; speedup 1.0000x reference)
//
#include <hip/hip_runtime.h>
#include <hip/hip_bf16.h>

// Decoder: B=1024, C=8, T=32, E=128, H=256, SEG=64, STEP=32, SIG=1056. f32 I/O.
// Wc = Winv@W2 (64x256), bc = Winv@b2+binv. Per (b,c):
//   Hm = relu(X W1^T + b1); S = Hm Wc^T + bc; sig = overlap-add(S)/counter;
//   out[b] = conv1d_{C->1,k=3,pad1}(sig) + bconv.
// R25: 12-wave shared-W1 split. R24 (4-wave split) lost because GEMM1's B
//   moved LDS->L2 and per-wave work dropped 4x. R23 fused is pinned at 2
//   waves/SIMD (8-wave block + 138KB LDS). This round: 768-thr blocks (12
//   waves) x 256 = 1 block/CU, LDS = W1 64KB (staged once, shared by 12
//   waves) + HS 12x4.6KB = 122KB -> 12 waves/CU = 3 waves/SIMD. Reg cap
//   512/3 = 170 vs natural 176: trimmed by moving Wcpre loads AFTER GEMM1
//   (no 32-reg live range across it; pack+H-write+bh-read covers ~150cy,
//   and Wcpre is L1-hit after wave 0 of 12). Each wave: up to 3 (b,c) its
//   with R23's X-prefetch pipeline. Conv split out (R24-proven Sig+k_conv).
//   Fallback: R23 fused kernel if ws too small.

typedef __bf16 bf16x8 __attribute__((ext_vector_type(8)));
typedef float  f32x4  __attribute__((ext_vector_type(4)));
typedef unsigned int u32;
typedef u32 u32x2 __attribute__((ext_vector_type(2)));

// ---- fused-kernel LDS map (fallback path) ----
#define L_W1   0        // 65536 B  W1 frag layout
#define L_HS   65536    // 36864 B  8 waves x [32][72] bf16 H; S alias [32][68]
#define L_SGA  102400   // 17024 B  sigA bf16 [8][1064] (pads zeroed)
#define L_SGB  119424   // 17024 B  sigB bf16 [8][1064]
#define L_B1   136448   // 1024 B
#define L_BC   137472   // 256 B
#define L_WV   137728   // 128 B
#define LDS_SZ 137856

// ---- 12-wave split-kernel LDS map ----
#define LB_HS  0        // 55296 B  12 waves x [32][72] bf16 H; S alias [32][68]
#define LB_W1  55296    // 65536 B  W1 frag layout (staged once per block)
#define LB_B1  120832   // 1024 B
#define LB_BC  121856   // 256 B
#define LB_SZ  122112   // <= 163840 -> 1 block/CU, 12 waves = 3/SIMD

// LDS-only barrier: waves' DS writes visible, global loads stay in flight.
#define BAR_LDS() do {                                              \
    __builtin_amdgcn_sched_barrier(0);                              \
    asm volatile("s_waitcnt lgkmcnt(0)" ::: "memory");              \
    __builtin_amdgcn_s_barrier();                                   \
    __builtin_amdgcn_sched_barrier(0);                              \
  } while (0)

static __device__ __forceinline__ bf16x8 cvt8(f32x4 a, f32x4 b) {
  bf16x8 r;
  r[0] = (__bf16)a[0]; r[1] = (__bf16)a[1]; r[2] = (__bf16)a[2]; r[3] = (__bf16)a[3];
  r[4] = (__bf16)b[0]; r[5] = (__bf16)b[1]; r[6] = (__bf16)b[2]; r[7] = (__bf16)b[3];
  return r;
}
static __device__ __forceinline__ u32 packbf2(float a, float b) {
  union { __hip_bfloat16 h; unsigned short s; } ua, ub;
  ua.h = __float2bfloat16(a); ub.h = __float2bfloat16(b);
  return (u32)ua.s | ((u32)ub.s << 16);
}
static __device__ __forceinline__ float lo16f(u32 w) { return __uint_as_float(w << 16); }
static __device__ __forceinline__ float hi16f(u32 w) { return __uint_as_float(w & 0xffff0000u); }

// ---- prep: Wc = Winv@W2 frag layout; bc = Winv@b2 + binv; W1 bf16 frags ----
// (R21-verified W1pre layout: entry p8 = fnc<<10|fnt<<8|fks<<6|fg<<4|fq)
__global__ __launch_bounds__(256) void k_precomp(
    const float* __restrict__ W1,
    const float* __restrict__ W2, const float* __restrict__ b2,
    const float* __restrict__ Winv, const float* __restrict__ binv,
    __hip_bfloat16* __restrict__ Wcpre, __hip_bfloat16* __restrict__ W1pre,
    float* __restrict__ bc) {
  __shared__ float wrow[128];
  const int s = blockIdx.x, h = threadIdx.x;
  if (h < 64) {
    const int p8 = s * 64 + h;
    const int fq = p8 & 15, fg = (p8 >> 4) & 3, fks = (p8 >> 6) & 3;
    const int fnt = (p8 >> 8) & 3, fnc = (p8 >> 10) & 3;
    const float* src = W1 + (fnc * 64 + fnt * 16 + fq) * 128 + fks * 32 + fg * 8;
    *reinterpret_cast<bf16x8*>(W1pre + p8 * 8) =
        cvt8(*reinterpret_cast<const f32x4*>(src),
             *reinterpret_cast<const f32x4*>(src + 4));
  }
  if (h < 128) wrow[h] = Winv[s * 128 + h];
  __syncthreads();
  float acc = 0.f;
  #pragma unroll 8
  for (int e = 0; e < 128; ++e) acc = fmaf(wrow[e], W2[e * 256 + h], acc);
  const int nc = h >> 6, ks2 = (h >> 5) & 1, g = (h >> 3) & 3, j = h & 7;
  const int nt2 = s >> 4, q = s & 15;
  Wcpre[((((nc * 2 + ks2) * 4 + nt2) * 4 + g) * 16 + q) * 8 + j] = __float2bfloat16(acc);
  if (h == 0) {
    float a = binv[s];
    for (int e = 0; e < 128; ++e) a = fmaf(wrow[e], b2[e], a);
    bc[s] = a;
  }
}

// ---- kernel A: 12 waves share LDS W1; each wave streams (b,c) pairs -------
__global__ __launch_bounds__(768)
void k_gemm_s2(const float* __restrict__ X,      // (1024,8,32,128)
               const __hip_bfloat16* __restrict__ W1p,     // frag layout (bf16)
               const float* __restrict__ b1,     // (256)
               const __hip_bfloat16* __restrict__ Wcpre,   // frag layout, L1/L2
               const float* __restrict__ bcp,    // (64)
               __hip_bfloat16* __restrict__ Sig) // (1024,8,1056) bf16
{
  __shared__ __align__(16) char smem[LB_SZ];
  const int tid = threadIdx.x;
  const int wave = tid >> 6, lane = tid & 63;
  const int q = lane & 15, g = lane >> 4;

  int idx = blockIdx.x * 12 + wave;     // flat (b,c): b = idx>>3, c = idx&7

  f32x4 xa[16];
  #define LOADX(ii) do {                                                        \
    const float* _xs = X + ((size_t)(ii)) * 4096;                               \
    _Pragma("unroll")                                                           \
    for (int _mt = 0; _mt < 2; ++_mt)                                           \
      _Pragma("unroll")                                                         \
      for (int _ks = 0; _ks < 4; ++_ks) {                                       \
        const float* _s = _xs + (_mt * 16 + q) * 128 + _ks * 32 + g * 8;        \
        xa[(_mt * 4 + _ks) * 2 + 0] = *reinterpret_cast<const f32x4*>(_s);      \
        xa[(_mt * 4 + _ks) * 2 + 1] = *reinterpret_cast<const f32x4*>(_s + 4);  \
      } } while (0)

  // issue it-0 X loads FIRST; they fly under W1 staging + barrier
  if (idx < 8192) LOADX(idx);

  // ---- stage W1 frags (pre-converted bf16, linear entry copy) + biases ----
  #pragma unroll
  for (int i = 0; i < 6; ++i) {
    const int e = tid + 768 * i;
    if (e < 4096)
      *reinterpret_cast<bf16x8*>(smem + LB_W1 + e * 16) =
          *reinterpret_cast<const bf16x8*>(W1p + e * 8);
  }
  if (tid < 256)               ((float*)(smem + LB_B1))[tid]       = b1[tid];
  if (tid >= 256 && tid < 320) ((float*)(smem + LB_BC))[tid - 256] = bcp[tid - 256];
  BAR_LDS();   // one-time: LDS writes visible; xa loads stay in flight

  __hip_bfloat16* Hb = reinterpret_cast<__hip_bfloat16*>(smem + LB_HS) + wave * 2304;
  const float* smB1 = (const float*)(smem + LB_B1);
  const float* smBC = (const float*)(smem + LB_BC);

  #pragma unroll 1
  for (int it = 0; it < 3; ++it) {
    const int nidx = idx + 3072;        // 256 blocks x 12 waves
    if (idx < 8192) {
      // consume prefetched X -> bf16 frags (xa dead afterwards)
      bf16x8 af[2][4];
      #pragma unroll
      for (int f = 0; f < 8; ++f) af[f >> 2][f & 3] = cvt8(xa[2 * f], xa[2 * f + 1]);

      f32x4 acc2[2][4] = {};   // S^T frag: col t = mt*16+q, row s = nt2*16+4g+i

      #pragma unroll 1         // block cross-chunk load hoisting (reg pressure)
      for (int nc = 0; nc < 4; ++nc) {
        // GEMM1 chunk (swapped): D = W1tile @ X^T -> col=t=q, row=h=4g+i
        f32x4 acc1[2][4] = {};
        #pragma unroll
        for (int ks = 0; ks < 4; ++ks) {
          bf16x8 bw[4];
          #pragma unroll
          for (int nt = 0; nt < 4; ++nt)
            bw[nt] = *reinterpret_cast<const bf16x8*>(
                smem + LB_W1 + (((nc * 4 + nt) * 4 + ks) << 10) + lane * 16);
          __builtin_amdgcn_s_setprio(1);
          #pragma unroll
          for (int nt = 0; nt < 4; ++nt) {
            acc1[0][nt] = __builtin_amdgcn_mfma_f32_16x16x32_bf16(bw[nt], af[0][ks], acc1[0][nt], 0, 0, 0);
            acc1[1][nt] = __builtin_amdgcn_mfma_f32_16x16x32_bf16(bw[nt], af[1][ks], acc1[1][nt], 0, 0, 0);
          }
          __builtin_amdgcn_s_setprio(0);
        }
        // Wcpre frags issued HERE: covered by pack + H-write + bh-read
        // (~150cy), no 32-reg live range across GEMM1 (3/SIMD reg cap),
        // and L1-hit after the first of 12 waves touches them.
        bf16x8 bw2f[2][4];
        #pragma unroll
        for (int ks2 = 0; ks2 < 2; ++ks2)
          #pragma unroll
          for (int nt2 = 0; nt2 < 4; ++nt2)
            bw2f[ks2][nt2] = *reinterpret_cast<const bf16x8*>(
                Wcpre + ((nc * 2 + ks2) * 4 + nt2) * 512 + lane * 8);
        // +b1, relu -> H chunk [32 t][72 h'], packed b64 writes
        #pragma unroll
        for (int nt = 0; nt < 4; ++nt) {
          const f32x4 b1q = *reinterpret_cast<const f32x4*>(smB1 + nc * 64 + nt * 16 + 4 * g);
          #pragma unroll
          for (int mt = 0; mt < 2; ++mt) {
            u32x2 w;
            w[0] = packbf2(fmaxf(acc1[mt][nt][0] + b1q[0], 0.f),
                           fmaxf(acc1[mt][nt][1] + b1q[1], 0.f));
            w[1] = packbf2(fmaxf(acc1[mt][nt][2] + b1q[2], 0.f),
                           fmaxf(acc1[mt][nt][3] + b1q[3], 0.f));
            *reinterpret_cast<u32x2*>(Hb + (mt * 16 + q) * 72 + nt * 16 + 4 * g) = w;
          }
        }
        // GEMM2 partial (swapped): D = Wc @ H^T -> col=t=q, row=s=4g+i
        #pragma unroll
        for (int ks2 = 0; ks2 < 2; ++ks2) {
          bf16x8 bh[2];
          #pragma unroll
          for (int mt = 0; mt < 2; ++mt)
            bh[mt] = *reinterpret_cast<const bf16x8*>(Hb + (mt * 16 + q) * 72 + ks2 * 32 + g * 8);
          __builtin_amdgcn_s_setprio(1);
          #pragma unroll
          for (int nt2 = 0; nt2 < 4; ++nt2) {
            acc2[0][nt2] = __builtin_amdgcn_mfma_f32_16x16x32_bf16(bw2f[ks2][nt2], bh[0], acc2[0][nt2], 0, 0, 0);
            acc2[1][nt2] = __builtin_amdgcn_mfma_f32_16x16x32_bf16(bw2f[ks2][nt2], bh[1], acc2[1][nt2], 0, 0, 0);
          }
          __builtin_amdgcn_s_setprio(0);
        }
      }

      // next (b,c) X prefetch AFTER all Wcpre loads (in-order vmcnt), while
      // accs/bw are dead -> xa's 64 regs never overlap the GEMM-phase peak.
      if (it < 2 && nidx < 8192) LOADX(nidx);

      // per-wave: S -> own H region [32 t][68 s] (packed b64)
      __hip_bfloat16* Sl = Hb;
      #pragma unroll
      for (int nt2 = 0; nt2 < 4; ++nt2) {
        const f32x4 bcq = *reinterpret_cast<const f32x4*>(smBC + nt2 * 16 + 4 * g);
        #pragma unroll
        for (int mt = 0; mt < 2; ++mt) {
          u32x2 w;
          w[0] = packbf2(acc2[mt][nt2][0] + bcq[0], acc2[mt][nt2][1] + bcq[1]);
          w[1] = packbf2(acc2[mt][nt2][2] + bcq[2], acc2[mt][nt2][3] + bcq[3]);
          *reinterpret_cast<u32x2*>(Sl + (mt * 16 + q) * 68 + nt2 * 16 + 4 * g) = w;
        }
      }

      // overlap-add gather + normalize -> global sig[idx][0..1055], 4/lane
      {
        __hip_bfloat16* sigc = Sig + (size_t)idx * 1056;
        #pragma unroll
        for (int w = 0; w < 5; ++w) {
          const int u = w * 64 + lane;
          if (u < 264) {
            const int p = 4 * u, t = p >> 5, j = p & 31;
            u32x2 r1 = {0u, 0u}, r2 = {0u, 0u};
            if (t < 32) r1 = *reinterpret_cast<const u32x2*>(Sl + t * 68 + j);
            if (t > 0)  r2 = *reinterpret_cast<const u32x2*>(Sl + (t - 1) * 68 + j + 32);
            const float nrm = (t == 0 || t == 32) ? 1.f : 0.5f;
            u32x2 wv;
            wv[0] = packbf2(nrm * (lo16f(r1[0]) + lo16f(r2[0])),
                            nrm * (hi16f(r1[0]) + hi16f(r2[0])));
            wv[1] = packbf2(nrm * (lo16f(r1[1]) + lo16f(r2[1])),
                            nrm * (hi16f(r1[1]) + hi16f(r2[1])));
            *reinterpret_cast<u32x2*>(sigc + p) = wv;
          }
        }
      }
    }
    idx = nidx;
  }
  #undef LOADX
}

// ---- kernel B: conv1d C->1, k=3, pad1 over sig; one block per batch -------
__global__ __launch_bounds__(256)
void k_conv(const __hip_bfloat16* __restrict__ Sig,   // (1024,8,1056) bf16
            const float* __restrict__ Wcv, const float* __restrict__ bcv,
            float* __restrict__ Out) {                // (1024,1056) f32
  __shared__ float wv[25];
  if (threadIdx.x < 24) wv[threadIdx.x] = Wcv[threadIdx.x];
  if (threadIdx.x == 24) wv[24] = bcv[0];
  __syncthreads();
  const int b = blockIdx.x;
  const float bconv = wv[24];
  #pragma unroll 1
  for (int rr = 0; rr < 2; ++rr) {
    const int u = threadIdx.x + rr * 256;
    if (u < 264) {
      const int p0 = 4 * u;
      f32x4 acc = {bconv, bconv, bconv, bconv};
      #pragma unroll
      for (int cc = 0; cc < 8; ++cc) {
        const __hip_bfloat16* row = Sig + (size_t)(b * 8 + cc) * 1056;
        const u32 wm = (p0 > 0) ? *reinterpret_cast<const u32*>(row + p0 - 2) : 0u;
        const u32x2 wc = *reinterpret_cast<const u32x2*>(row + p0);
        const u32 wr = (p0 + 4 < 1056) ? *reinterpret_cast<const u32*>(row + p0 + 4) : 0u;
        const float l  = hi16f(wm);
        const float a0 = lo16f(wc[0]), a1 = hi16f(wc[0]);
        const float a2 = lo16f(wc[1]), a3 = hi16f(wc[1]);
        const float r  = lo16f(wr);
        const float w0 = wv[cc * 3], w1 = wv[cc * 3 + 1], w2 = wv[cc * 3 + 2];
        acc[0] = fmaf(w0, l,  fmaf(w1, a0, fmaf(w2, a1, acc[0])));
        acc[1] = fmaf(w0, a0, fmaf(w1, a1, fmaf(w2, a2, acc[1])));
        acc[2] = fmaf(w0, a1, fmaf(w1, a2, fmaf(w2, a3, acc[2])));
        acc[3] = fmaf(w0, a2, fmaf(w1, a3, fmaf(w2, r,  acc[3])));
      }
      *reinterpret_cast<f32x4*>(Out + (size_t)b * 1056 + p0) = acc;
    }
  }
}

// ---- fallback: R23 fused kernel (proven 59.1us), used if ws too small ------
__global__ __launch_bounds__(512)
__attribute__((amdgpu_waves_per_eu(2, 2)))
void k_gemm_fused(const float* __restrict__ X,
                  const float* __restrict__ W1,
                  const float* __restrict__ b1,
                  const __hip_bfloat16* __restrict__ Wcpre,
                  const float* __restrict__ bcp,
                  const float* __restrict__ Wcv,
                  const float* __restrict__ bcv,
                  float* __restrict__ Out) {
  extern __shared__ __align__(16) char smem[];
  const int tid = threadIdx.x;
  const int wave = tid >> 6, lane = tid & 63;
  const int q = lane & 15, g = lane >> 4;
  const int c = wave;
  const int b0 = blockIdx.x * 4;

  f32x4 xa[16];
  #define LOADX(bb) do {                                                        \
    _Pragma("unroll")                                                           \
    for (int _mt = 0; _mt < 2; ++_mt) {                                         \
      const float* _s = X + ((size_t)((bb) * 8 + c)) * 4096                     \
                          + (_mt * 16 + q) * 128 + g * 8;                       \
      _Pragma("unroll")                                                         \
      for (int _ks = 0; _ks < 4; ++_ks) {                                       \
        xa[(_mt * 4 + _ks) * 2 + 0] = *reinterpret_cast<const f32x4*>(_s + _ks * 32);     \
        xa[(_mt * 4 + _ks) * 2 + 1] = *reinterpret_cast<const f32x4*>(_s + _ks * 32 + 4); \
      } } } while (0)

  LOADX(b0);

  #pragma unroll
  for (int i = 0; i < 8; ++i) {
    const int p8 = tid + i * 512;
    const int fq = p8 & 15, fg = (p8 >> 4) & 3, fks = (p8 >> 6) & 3;
    const int fnt = (p8 >> 8) & 3, fnc = (p8 >> 10) & 3;
    const float* src = W1 + (fnc * 64 + fnt * 16 + fq) * 128 + fks * 32 + fg * 8;
    *reinterpret_cast<bf16x8*>(smem + L_W1 + p8 * 16) =
        cvt8(*reinterpret_cast<const f32x4*>(src),
             *reinterpret_cast<const f32x4*>(src + 4));
  }
  {
    if (tid < 256)               ((float*)(smem + L_B1))[tid]       = b1[tid];
    if (tid >= 256 && tid < 320) ((float*)(smem + L_BC))[tid - 256] = bcp[tid - 256];
    if (tid >= 320 && tid < 344) ((float*)(smem + L_WV))[tid - 320] = Wcv[tid - 320];
    if (tid == 344)              ((float*)(smem + L_WV))[24]        = bcv[0];
    if (tid >= 384 && tid < 448) {
      const int t = tid - 384, buf = t >> 5, cc = (t & 31) >> 2, k = t & 3;
      *reinterpret_cast<u32*>(
          reinterpret_cast<__hip_bfloat16*>(smem + (buf ? L_SGB : L_SGA))
          + cc * 1064 + 1056 + 2 * k) = 0u;
    }
  }
  BAR_LDS();

  __hip_bfloat16* Hb = reinterpret_cast<__hip_bfloat16*>(smem + L_HS) + wave * 2304;
  const float* smB1 = (const float*)(smem + L_B1);
  const float* smBC = (const float*)(smem + L_BC);
  const float* smWV = (const float*)(smem + L_WV);

  #pragma unroll 1
  for (int it = 0; it < 4; ++it) {
    bf16x8 af[2][4];
    #pragma unroll
    for (int f = 0; f < 8; ++f) af[f >> 2][f & 3] = cvt8(xa[2 * f], xa[2 * f + 1]);

    f32x4 acc2[2][4] = {};

    #pragma unroll 1
    for (int nc = 0; nc < 4; ++nc) {
      bf16x8 bw2f[2][4];
      #pragma unroll
      for (int ks2 = 0; ks2 < 2; ++ks2)
        #pragma unroll
        for (int nt2 = 0; nt2 < 4; ++nt2)
          bw2f[ks2][nt2] = *reinterpret_cast<const bf16x8*>(
              Wcpre + ((nc * 2 + ks2) * 4 + nt2) * 512 + lane * 8);

      f32x4 acc1[2][4] = {};
      #pragma unroll
      for (int ks = 0; ks < 4; ++ks) {
        bf16x8 bw[4];
        #pragma unroll
        for (int nt = 0; nt < 4; ++nt)
          bw[nt] = *reinterpret_cast<const bf16x8*>(
              smem + L_W1 + (((nc * 4 + nt) * 4 + ks) << 10) + lane * 16);
        __builtin_amdgcn_s_setprio(1);
        #pragma unroll
        for (int nt = 0; nt < 4; ++nt) {
          acc1[0][nt] = __builtin_amdgcn_mfma_f32_16x16x32_bf16(bw[nt], af[0][ks], acc1[0][nt], 0, 0, 0);
          acc1[1][nt] = __builtin_amdgcn_mfma_f32_16x16x32_bf16(bw[nt], af[1][ks], acc1[1][nt], 0, 0, 0);
        }
        __builtin_amdgcn_s_setprio(0);
      }
      #pragma unroll
      for (int nt = 0; nt < 4; ++nt) {
        const f32x4 b1q = *reinterpret_cast<const f32x4*>(smB1 + nc * 64 + nt * 16 + 4 * g);
        #pragma unroll
        for (int mt = 0; mt < 2; ++mt) {
          u32x2 w;
          w[0] = packbf2(fmaxf(acc1[mt][nt][0] + b1q[0], 0.f),
                         fmaxf(acc1[mt][nt][1] + b1q[1], 0.f));
          w[1] = packbf2(fmaxf(acc1[mt][nt][2] + b1q[2], 0.f),
                         fmaxf(acc1[mt][nt][3] + b1q[3], 0.f));
          *reinterpret_cast<u32x2*>(Hb + (mt * 16 + q) * 72 + nt * 16 + 4 * g) = w;
        }
      }
      #pragma unroll
      for (int ks2 = 0; ks2 < 2; ++ks2) {
        bf16x8 bh[2];
        #pragma unroll
        for (int mt = 0; mt < 2; ++mt)
          bh[mt] = *reinterpret_cast<const bf16x8*>(Hb + (mt * 16 + q) * 72 + ks2 * 32 + g * 8);
        __builtin_amdgcn_s_setprio(1);
        #pragma unroll
        for (int nt2 = 0; nt2 < 4; ++nt2) {
          acc2[0][nt2] = __builtin_amdgcn_mfma_f32_16x16x32_bf16(bw2f[ks2][nt2], bh[0], acc2[0][nt2], 0, 0, 0);
          acc2[1][nt2] = __builtin_amdgcn_mfma_f32_16x16x32_bf16(bw2f[ks2][nt2], bh[1], acc2[1][nt2], 0, 0, 0);
        }
        __builtin_amdgcn_s_setprio(0);
      }
    }

    if (it < 3) LOADX(b0 + it + 1);

    __hip_bfloat16* Sl = Hb;
    #pragma unroll
    for (int nt2 = 0; nt2 < 4; ++nt2) {
      const f32x4 bcq = *reinterpret_cast<const f32x4*>(smBC + nt2 * 16 + 4 * g);
      #pragma unroll
      for (int mt = 0; mt < 2; ++mt) {
        u32x2 w;
        w[0] = packbf2(acc2[mt][nt2][0] + bcq[0], acc2[mt][nt2][1] + bcq[1]);
        w[1] = packbf2(acc2[mt][nt2][2] + bcq[2], acc2[mt][nt2][3] + bcq[3]);
        *reinterpret_cast<u32x2*>(Sl + (mt * 16 + q) * 68 + nt2 * 16 + 4 * g) = w;
      }
    }

    {
      __hip_bfloat16* sigc = reinterpret_cast<__hip_bfloat16*>(
          smem + ((it & 1) ? L_SGB : L_SGA)) + c * 1064;
      #pragma unroll
      for (int w = 0; w < 5; ++w) {
        const int u = w * 64 + lane;
        if (u < 264) {
          const int p = 4 * u, t = p >> 5, j = p & 31;
          u32x2 r1 = {0u, 0u}, r2 = {0u, 0u};
          if (t < 32) r1 = *reinterpret_cast<const u32x2*>(Sl + t * 68 + j);
          if (t > 0)  r2 = *reinterpret_cast<const u32x2*>(Sl + (t - 1) * 68 + j + 32);
          const float nrm = (t == 0 || t == 32) ? 1.f : 0.5f;
          u32x2 wv;
          wv[0] = packbf2(nrm * (lo16f(r1[0]) + lo16f(r2[0])),
                          nrm * (hi16f(r1[0]) + hi16f(r2[0])));
          wv[1] = packbf2(nrm * (lo16f(r1[1]) + lo16f(r2[1])),
                          nrm * (hi16f(r1[1]) + hi16f(r2[1])));
          *reinterpret_cast<u32x2*>(sigc + p) = wv;
        }
      }
    }

    if (it & 1) {
      BAR_LDS();
      const float bconv = smWV[24];
      #pragma unroll 1
      for (int rr = 0; rr < 2; ++rr) {
        const int u = tid + rr * 512;
        if (u < 528) {
          const int half = (u >= 264) ? 1 : 0;
          const __hip_bfloat16* sg = reinterpret_cast<const __hip_bfloat16*>(
              smem + (half ? L_SGB : L_SGA));
          const int p0 = (u - half * 264) * 4;
          f32x4 acc = {bconv, bconv, bconv, bconv};
          #pragma unroll
          for (int cc = 0; cc < 8; ++cc) {
            const __hip_bfloat16* row = sg + cc * 1064;
            const u32 wm = (p0 > 0) ? *reinterpret_cast<const u32*>(row + p0 - 2) : 0u;
            const u32x2 wc = *reinterpret_cast<const u32x2*>(row + p0);
            const u32 wr = *reinterpret_cast<const u32*>(row + p0 + 4);
            const float l  = hi16f(wm);
            const float a0 = lo16f(wc[0]), a1 = hi16f(wc[0]);
            const float a2 = lo16f(wc[1]), a3 = hi16f(wc[1]);
            const float r  = lo16f(wr);
            const float w0 = smWV[cc * 3], w1 = smWV[cc * 3 + 1], w2 = smWV[cc * 3 + 2];
            acc[0] = fmaf(w0, l,  fmaf(w1, a0, fmaf(w2, a1, acc[0])));
            acc[1] = fmaf(w0, a0, fmaf(w1, a1, fmaf(w2, a2, acc[1])));
            acc[2] = fmaf(w0, a1, fmaf(w1, a2, fmaf(w2, a3, acc[2])));
            acc[3] = fmaf(w0, a2, fmaf(w1, a3, fmaf(w2, r,  acc[3])));
          }
          *reinterpret_cast<f32x4*>(
              Out + (size_t)(b0 + it - 1 + half) * 1056 + p0) = acc;
        }
      }
      if (it != 3) BAR_LDS();
    }
  }
  #undef LOADX
}

extern "C" void kernel_launch(void* const* d_in, const int* in_sizes, int n_in,
                              void* d_out, int out_size, void* d_ws, size_t ws_size,
                              hipStream_t stream) {
  const float* X    = (const float*)d_in[0];
  const float* W1   = (const float*)d_in[1];
  const float* b1   = (const float*)d_in[2];
  const float* W2   = (const float*)d_in[3];
  const float* b2   = (const float*)d_in[4];
  const float* Winv = (const float*)d_in[5];
  const float* binv = (const float*)d_in[6];
  const float* Wcv  = (const float*)d_in[7];
  const float* bcv  = (const float*)d_in[8];

  __hip_bfloat16* W1pre = (__hip_bfloat16*)d_ws;                     // 65536 B
  __hip_bfloat16* Wcpre = (__hip_bfloat16*)((char*)d_ws + 65536);    // 32768 B
  float*          bcp   = (float*)((char*)d_ws + 98304);             // 256 B
  __hip_bfloat16* Sig   = (__hip_bfloat16*)((char*)d_ws + 131072);   // 17301504 B
  const size_t need = 131072 + (size_t)1024 * 8 * 1056 * 2;

  k_precomp<<<64, 256, 0, stream>>>(W1, W2, b2, Winv, binv, Wcpre, W1pre, bcp);
  if (ws_size >= need) {
    k_gemm_s2<<<256, 768, 0, stream>>>(X, W1pre, b1, Wcpre, bcp, Sig);
    k_conv<<<1024, 256, 0, stream>>>(Sig, Wcv, bcv, (float*)d_out);
  } else {
    k_gemm_fused<<<256, 512, LDS_SZ, stream>>>(X, W1, b1, Wcpre, bcp, Wcv, bcv,
                                               (float*)d_out);
  }
}

// Round 6
// 77.531 us; speedup vs baseline: 1.3217x; 1.3217x over previous
//
#include <hip/hip_runtime.h>
#include <hip/hip_bf16.h>

// Decoder: B=1024, C=8, T=32, E=128, H=256, SEG=64, STEP=32, SIG=1056. f32 I/O.
// Wc = Winv@W2 (64x256), bc = Winv@b2+binv. Per (b,c):
//   Hm = relu(X W1^T + b1); S = Hm Wc^T + bc; sig = overlap-add(S)/counter;
//   out[b] = conv1d_{C->1,k=3,pad1}(sig) + bconv.
// R26: HALF-TILE waves. R21/R22/R25 all died the same way: 32-token waves
//   have a ~176-190 reg natural peak; any cap (128 or 170) -> allocator
//   spill collapse (R25: 100MB scratch despite 148 alloc'd). Fix the
//   FOOTPRINT, not the cap: 16-token waves halve xa/af/acc1/acc2 ->
//   peak ~110-130, 40+ regs slack under the 3/SIMD cap of 170.
//   k_gemm_s3: 768 thr = 12 waves = 6 (b,c)-pairs; W1 in LDS (shared,
//   R24 lesson); Sig -> global + k_conv (R24-proven). S per pair,
//   double-buffered by it&1; ONE LDS barrier per it covers the
//   cross-wave gather reads; double-buffer covers drift. LDS 146.7KB ->
//   1 block/CU, 12 waves/CU = 3/SIMD (vs R23's 2).
//   Fallback: R23 fused kernel (proven 59.1us) if ws too small.

typedef __bf16 bf16x8 __attribute__((ext_vector_type(8)));
typedef float  f32x4  __attribute__((ext_vector_type(4)));
typedef unsigned int u32;
typedef u32 u32x2 __attribute__((ext_vector_type(2)));

// ---- fused-kernel LDS map (fallback path) ----
#define L_W1   0        // 65536 B  W1 frag layout
#define L_HS   65536    // 36864 B  8 waves x [32][72] bf16 H; S alias [32][68]
#define L_SGA  102400   // 17024 B  sigA bf16 [8][1064] (pads zeroed)
#define L_SGB  119424   // 17024 B  sigB bf16 [8][1064]
#define L_B1   136448   // 1024 B
#define L_BC   137472   // 256 B
#define L_WV   137728   // 128 B
#define LDS_SZ 137856

// ---- R26 12-wave half-tile LDS map ----
#define LC_H   0        // 27648 B  12 waves x [16][72] bf16 H (private)
#define LC_S   27648    // 52224 B  6 pairs x 2 bufs x [32][68] bf16 S
#define LC_W1  79872    // 65536 B  W1 frag layout (staged once, shared)
#define LC_B1  145408   // 1024 B
#define LC_BC  146432   // 256 B
#define LC_SZ  146688   // <= 163840 -> 1 block/CU, 12 waves = 3/SIMD

// LDS-only barrier: waves' DS writes visible, global loads stay in flight.
#define BAR_LDS() do {                                              \
    __builtin_amdgcn_sched_barrier(0);                              \
    asm volatile("s_waitcnt lgkmcnt(0)" ::: "memory");              \
    __builtin_amdgcn_s_barrier();                                   \
    __builtin_amdgcn_sched_barrier(0);                              \
  } while (0)

static __device__ __forceinline__ bf16x8 cvt8(f32x4 a, f32x4 b) {
  bf16x8 r;
  r[0] = (__bf16)a[0]; r[1] = (__bf16)a[1]; r[2] = (__bf16)a[2]; r[3] = (__bf16)a[3];
  r[4] = (__bf16)b[0]; r[5] = (__bf16)b[1]; r[6] = (__bf16)b[2]; r[7] = (__bf16)b[3];
  return r;
}
static __device__ __forceinline__ u32 packbf2(float a, float b) {
  union { __hip_bfloat16 h; unsigned short s; } ua, ub;
  ua.h = __float2bfloat16(a); ub.h = __float2bfloat16(b);
  return (u32)ua.s | ((u32)ub.s << 16);
}
static __device__ __forceinline__ float lo16f(u32 w) { return __uint_as_float(w << 16); }
static __device__ __forceinline__ float hi16f(u32 w) { return __uint_as_float(w & 0xffff0000u); }

// ---- prep: Wc = Winv@W2 frag layout; bc = Winv@b2 + binv; W1 bf16 frags ----
// (R21-verified W1pre layout: entry p8 = fnc<<10|fnt<<8|fks<<6|fg<<4|fq)
__global__ __launch_bounds__(256) void k_precomp(
    const float* __restrict__ W1,
    const float* __restrict__ W2, const float* __restrict__ b2,
    const float* __restrict__ Winv, const float* __restrict__ binv,
    __hip_bfloat16* __restrict__ Wcpre, __hip_bfloat16* __restrict__ W1pre,
    float* __restrict__ bc) {
  __shared__ float wrow[128];
  const int s = blockIdx.x, h = threadIdx.x;
  if (h < 64) {
    const int p8 = s * 64 + h;
    const int fq = p8 & 15, fg = (p8 >> 4) & 3, fks = (p8 >> 6) & 3;
    const int fnt = (p8 >> 8) & 3, fnc = (p8 >> 10) & 3;
    const float* src = W1 + (fnc * 64 + fnt * 16 + fq) * 128 + fks * 32 + fg * 8;
    *reinterpret_cast<bf16x8*>(W1pre + p8 * 8) =
        cvt8(*reinterpret_cast<const f32x4*>(src),
             *reinterpret_cast<const f32x4*>(src + 4));
  }
  if (h < 128) wrow[h] = Winv[s * 128 + h];
  __syncthreads();
  float acc = 0.f;
  #pragma unroll 8
  for (int e = 0; e < 128; ++e) acc = fmaf(wrow[e], W2[e * 256 + h], acc);
  const int nc = h >> 6, ks2 = (h >> 5) & 1, g = (h >> 3) & 3, j = h & 7;
  const int nt2 = s >> 4, q = s & 15;
  Wcpre[((((nc * 2 + ks2) * 4 + nt2) * 4 + g) * 16 + q) * 8 + j] = __float2bfloat16(acc);
  if (h == 0) {
    float a = binv[s];
    for (int e = 0; e < 128; ++e) a = fmaf(wrow[e], b2[e], a);
    bc[s] = a;
  }
}

// ---- kernel A: 12 waves, HALF-(b,c) (16 tokens) each; 6 its ---------------
__global__ __launch_bounds__(768)
void k_gemm_s3(const float* __restrict__ X,      // (1024,8,32,128)
               const __hip_bfloat16* __restrict__ W1p,     // frag layout (bf16)
               const float* __restrict__ b1,     // (256)
               const __hip_bfloat16* __restrict__ Wcpre,   // frag layout, L1/L2
               const float* __restrict__ bcp,    // (64)
               __hip_bfloat16* __restrict__ Sig) // (1024,8,1056) bf16
{
  __shared__ __align__(16) char smem[LC_SZ];
  const int tid = threadIdx.x;
  const int wave = tid >> 6, lane = tid & 63;
  const int q = lane & 15, g = lane >> 4;
  const int mt = wave & 1;                // half index: tokens mt*16 + q
  const int pslot = wave >> 1;            // pair slot 0..5 (S buffer owner)

  int task = blockIdx.x * 12 + wave;      // task = pair*2 + mt; +3072/it

  // xa: 16 tokens x 128 e -> 8 f32x4 per lane (32 regs)
  f32x4 xa[8];
  #define LOADX(tt) do {                                                        \
    const float* _xs = X + ((size_t)((tt) >> 1)) * 4096                         \
                         + (((tt) & 1) * 16 + q) * 128 + g * 8;                 \
    _Pragma("unroll")                                                           \
    for (int _ks = 0; _ks < 4; ++_ks) {                                         \
      xa[_ks * 2 + 0] = *reinterpret_cast<const f32x4*>(_xs + _ks * 32);        \
      xa[_ks * 2 + 1] = *reinterpret_cast<const f32x4*>(_xs + _ks * 32 + 4);    \
    } } while (0)

  // issue it-0 X loads FIRST; they fly under W1 staging + barrier
  LOADX(task);

  // ---- stage W1 frags (pre-converted bf16, linear entry copy) + biases ----
  #pragma unroll
  for (int i = 0; i < 6; ++i) {
    const int e = tid + 768 * i;
    if (e < 4096)
      *reinterpret_cast<bf16x8*>(smem + LC_W1 + e * 16) =
          *reinterpret_cast<const bf16x8*>(W1p + e * 8);
  }
  if (tid < 256)               ((float*)(smem + LC_B1))[tid]       = b1[tid];
  if (tid >= 256 && tid < 320) ((float*)(smem + LC_BC))[tid - 256] = bcp[tid - 256];
  BAR_LDS();   // one-time: LDS writes visible; xa loads stay in flight

  __hip_bfloat16* Hb = reinterpret_cast<__hip_bfloat16*>(smem + LC_H) + wave * 1152;
  const float* smB1 = (const float*)(smem + LC_B1);
  const float* smBC = (const float*)(smem + LC_BC);

  #pragma unroll 1
  for (int it = 0; it < 6; ++it) {
    // pair's S buffer for THIS it (double-buffered by it&1)
    __hip_bfloat16* Sb = reinterpret_cast<__hip_bfloat16*>(smem + LC_S)
                         + (pslot * 2 + (it & 1)) * 2176;
    const bool act = (task < 16384);
    if (act) {
      // consume prefetched X -> bf16 frags (xa dead afterwards)
      bf16x8 af[4];
      #pragma unroll
      for (int f = 0; f < 4; ++f) af[f] = cvt8(xa[2 * f], xa[2 * f + 1]);

      f32x4 acc2[4] = {};   // S^T frag: col t = mt*16+q, row s = nt2*16+4g+i

      #pragma unroll 1       // block cross-chunk load hoisting (reg pressure)
      for (int nc = 0; nc < 4; ++nc) {
        // prefetch GEMM2 B-frags; GEMM1 covers their L2 latency (R23-proven)
        bf16x8 bw2f[2][4];
        #pragma unroll
        for (int ks2 = 0; ks2 < 2; ++ks2)
          #pragma unroll
          for (int nt2 = 0; nt2 < 4; ++nt2)
            bw2f[ks2][nt2] = *reinterpret_cast<const bf16x8*>(
                Wcpre + ((nc * 2 + ks2) * 4 + nt2) * 512 + lane * 8);

        // GEMM1 chunk (swapped): D = W1tile @ X^T -> col=t=q, row=h=4g+i
        f32x4 acc1[4] = {};
        #pragma unroll
        for (int ks = 0; ks < 4; ++ks) {
          bf16x8 bw[4];
          #pragma unroll
          for (int nt = 0; nt < 4; ++nt)
            bw[nt] = *reinterpret_cast<const bf16x8*>(
                smem + LC_W1 + (((nc * 4 + nt) * 4 + ks) << 10) + lane * 16);
          __builtin_amdgcn_s_setprio(1);
          #pragma unroll
          for (int nt = 0; nt < 4; ++nt)
            acc1[nt] = __builtin_amdgcn_mfma_f32_16x16x32_bf16(bw[nt], af[ks], acc1[nt], 0, 0, 0);
          __builtin_amdgcn_s_setprio(0);
        }
        // +b1, relu -> private H [16 t][72 h'], packed b64 writes
        #pragma unroll
        for (int nt = 0; nt < 4; ++nt) {
          const f32x4 b1q = *reinterpret_cast<const f32x4*>(smB1 + nc * 64 + nt * 16 + 4 * g);
          u32x2 w;
          w[0] = packbf2(fmaxf(acc1[nt][0] + b1q[0], 0.f),
                         fmaxf(acc1[nt][1] + b1q[1], 0.f));
          w[1] = packbf2(fmaxf(acc1[nt][2] + b1q[2], 0.f),
                         fmaxf(acc1[nt][3] + b1q[3], 0.f));
          *reinterpret_cast<u32x2*>(Hb + q * 72 + nt * 16 + 4 * g) = w;
        }
        // GEMM2 partial (swapped): D = Wc @ H^T -> col=t=q, row=s=4g+i
        #pragma unroll
        for (int ks2 = 0; ks2 < 2; ++ks2) {
          const bf16x8 bh = *reinterpret_cast<const bf16x8*>(
              Hb + q * 72 + ks2 * 32 + g * 8);
          __builtin_amdgcn_s_setprio(1);
          #pragma unroll
          for (int nt2 = 0; nt2 < 4; ++nt2)
            acc2[nt2] = __builtin_amdgcn_mfma_f32_16x16x32_bf16(bw2f[ks2][nt2], bh, acc2[nt2], 0, 0, 0);
          __builtin_amdgcn_s_setprio(0);
        }
      }

      // next task's X prefetch AFTER all Wcpre loads (in-order vmcnt);
      // xa (32 regs) never overlaps the GEMM-phase register peak.
      if (it < 5 && task + 3072 < 16384) LOADX(task + 3072);

      // S (this half) -> pair buffer rows [mt*16 .. mt*16+16)
      #pragma unroll
      for (int nt2 = 0; nt2 < 4; ++nt2) {
        const f32x4 bcq = *reinterpret_cast<const f32x4*>(smBC + nt2 * 16 + 4 * g);
        u32x2 w;
        w[0] = packbf2(acc2[nt2][0] + bcq[0], acc2[nt2][1] + bcq[1]);
        w[1] = packbf2(acc2[nt2][2] + bcq[2], acc2[nt2][3] + bcq[3]);
        *reinterpret_cast<u32x2*>(Sb + (mt * 16 + q) * 68 + nt2 * 16 + 4 * g) = w;
      }
    }

    // pair's S complete (both halves) before cross-wave gather reads.
    // Double-buffer makes next-it S writes safe across this barrier.
    BAR_LDS();

    if (act) {
      // overlap-add gather + normalize -> global sig, split by half:
      // mt0: u in [0,128) (t 0..15); mt1: u in [128,264) (t 16..32)
      __hip_bfloat16* sigc = Sig + (size_t)(task >> 1) * 1056;
      #pragma unroll
      for (int w = 0; w < 3; ++w) {
        const int u = mt * 128 + w * 64 + lane;
        if ((mt == 0 && w < 2) || (mt == 1 && u < 264)) {
          const int p = 4 * u, t = p >> 5, j = p & 31;
          u32x2 r1 = {0u, 0u}, r2 = {0u, 0u};
          if (t < 32) r1 = *reinterpret_cast<const u32x2*>(Sb + t * 68 + j);
          if (t > 0)  r2 = *reinterpret_cast<const u32x2*>(Sb + (t - 1) * 68 + j + 32);
          const float nrm = (t == 0 || t == 32) ? 1.f : 0.5f;
          u32x2 wv;
          wv[0] = packbf2(nrm * (lo16f(r1[0]) + lo16f(r2[0])),
                          nrm * (hi16f(r1[0]) + hi16f(r2[0])));
          wv[1] = packbf2(nrm * (lo16f(r1[1]) + lo16f(r2[1])),
                          nrm * (hi16f(r1[1]) + hi16f(r2[1])));
          *reinterpret_cast<u32x2*>(sigc + p) = wv;
        }
      }
    }
    task += 3072;
  }
  #undef LOADX
}

// ---- kernel B: conv1d C->1, k=3, pad1 over sig; one block per batch -------
__global__ __launch_bounds__(256)
void k_conv(const __hip_bfloat16* __restrict__ Sig,   // (1024,8,1056) bf16
            const float* __restrict__ Wcv, const float* __restrict__ bcv,
            float* __restrict__ Out) {                // (1024,1056) f32
  __shared__ float wv[25];
  if (threadIdx.x < 24) wv[threadIdx.x] = Wcv[threadIdx.x];
  if (threadIdx.x == 24) wv[24] = bcv[0];
  __syncthreads();
  const int b = blockIdx.x;
  const float bconv = wv[24];
  #pragma unroll 1
  for (int rr = 0; rr < 2; ++rr) {
    const int u = threadIdx.x + rr * 256;
    if (u < 264) {
      const int p0 = 4 * u;
      f32x4 acc = {bconv, bconv, bconv, bconv};
      #pragma unroll
      for (int cc = 0; cc < 8; ++cc) {
        const __hip_bfloat16* row = Sig + (size_t)(b * 8 + cc) * 1056;
        const u32 wm = (p0 > 0) ? *reinterpret_cast<const u32*>(row + p0 - 2) : 0u;
        const u32x2 wc = *reinterpret_cast<const u32x2*>(row + p0);
        const u32 wr = (p0 + 4 < 1056) ? *reinterpret_cast<const u32*>(row + p0 + 4) : 0u;
        const float l  = hi16f(wm);
        const float a0 = lo16f(wc[0]), a1 = hi16f(wc[0]);
        const float a2 = lo16f(wc[1]), a3 = hi16f(wc[1]);
        const float r  = lo16f(wr);
        const float w0 = wv[cc * 3], w1 = wv[cc * 3 + 1], w2 = wv[cc * 3 + 2];
        acc[0] = fmaf(w0, l,  fmaf(w1, a0, fmaf(w2, a1, acc[0])));
        acc[1] = fmaf(w0, a0, fmaf(w1, a1, fmaf(w2, a2, acc[1])));
        acc[2] = fmaf(w0, a1, fmaf(w1, a2, fmaf(w2, a3, acc[2])));
        acc[3] = fmaf(w0, a2, fmaf(w1, a3, fmaf(w2, r,  acc[3])));
      }
      *reinterpret_cast<f32x4*>(Out + (size_t)b * 1056 + p0) = acc;
    }
  }
}

// ---- fallback: R23 fused kernel (proven 59.1us), used if ws too small ------
__global__ __launch_bounds__(512)
__attribute__((amdgpu_waves_per_eu(2, 2)))
void k_gemm_fused(const float* __restrict__ X,
                  const float* __restrict__ W1,
                  const float* __restrict__ b1,
                  const __hip_bfloat16* __restrict__ Wcpre,
                  const float* __restrict__ bcp,
                  const float* __restrict__ Wcv,
                  const float* __restrict__ bcv,
                  float* __restrict__ Out) {
  extern __shared__ __align__(16) char smem[];
  const int tid = threadIdx.x;
  const int wave = tid >> 6, lane = tid & 63;
  const int q = lane & 15, g = lane >> 4;
  const int c = wave;
  const int b0 = blockIdx.x * 4;

  f32x4 xa[16];
  #define LOADX(bb) do {                                                        \
    _Pragma("unroll")                                                           \
    for (int _mt = 0; _mt < 2; ++_mt) {                                         \
      const float* _s = X + ((size_t)((bb) * 8 + c)) * 4096                     \
                          + (_mt * 16 + q) * 128 + g * 8;                       \
      _Pragma("unroll")                                                         \
      for (int _ks = 0; _ks < 4; ++_ks) {                                       \
        xa[(_mt * 4 + _ks) * 2 + 0] = *reinterpret_cast<const f32x4*>(_s + _ks * 32);     \
        xa[(_mt * 4 + _ks) * 2 + 1] = *reinterpret_cast<const f32x4*>(_s + _ks * 32 + 4); \
      } } } while (0)

  LOADX(b0);

  #pragma unroll
  for (int i = 0; i < 8; ++i) {
    const int p8 = tid + i * 512;
    const int fq = p8 & 15, fg = (p8 >> 4) & 3, fks = (p8 >> 6) & 3;
    const int fnt = (p8 >> 8) & 3, fnc = (p8 >> 10) & 3;
    const float* src = W1 + (fnc * 64 + fnt * 16 + fq) * 128 + fks * 32 + fg * 8;
    *reinterpret_cast<bf16x8*>(smem + L_W1 + p8 * 16) =
        cvt8(*reinterpret_cast<const f32x4*>(src),
             *reinterpret_cast<const f32x4*>(src + 4));
  }
  {
    if (tid < 256)               ((float*)(smem + L_B1))[tid]       = b1[tid];
    if (tid >= 256 && tid < 320) ((float*)(smem + L_BC))[tid - 256] = bcp[tid - 256];
    if (tid >= 320 && tid < 344) ((float*)(smem + L_WV))[tid - 320] = Wcv[tid - 320];
    if (tid == 344)              ((float*)(smem + L_WV))[24]        = bcv[0];
    if (tid >= 384 && tid < 448) {
      const int t = tid - 384, buf = t >> 5, cc = (t & 31) >> 2, k = t & 3;
      *reinterpret_cast<u32*>(
          reinterpret_cast<__hip_bfloat16*>(smem + (buf ? L_SGB : L_SGA))
          + cc * 1064 + 1056 + 2 * k) = 0u;
    }
  }
  BAR_LDS();

  __hip_bfloat16* Hb = reinterpret_cast<__hip_bfloat16*>(smem + L_HS) + wave * 2304;
  const float* smB1 = (const float*)(smem + L_B1);
  const float* smBC = (const float*)(smem + L_BC);
  const float* smWV = (const float*)(smem + L_WV);

  #pragma unroll 1
  for (int it = 0; it < 4; ++it) {
    bf16x8 af[2][4];
    #pragma unroll
    for (int f = 0; f < 8; ++f) af[f >> 2][f & 3] = cvt8(xa[2 * f], xa[2 * f + 1]);

    f32x4 acc2[2][4] = {};

    #pragma unroll 1
    for (int nc = 0; nc < 4; ++nc) {
      bf16x8 bw2f[2][4];
      #pragma unroll
      for (int ks2 = 0; ks2 < 2; ++ks2)
        #pragma unroll
        for (int nt2 = 0; nt2 < 4; ++nt2)
          bw2f[ks2][nt2] = *reinterpret_cast<const bf16x8*>(
              Wcpre + ((nc * 2 + ks2) * 4 + nt2) * 512 + lane * 8);

      f32x4 acc1[2][4] = {};
      #pragma unroll
      for (int ks = 0; ks < 4; ++ks) {
        bf16x8 bw[4];
        #pragma unroll
        for (int nt = 0; nt < 4; ++nt)
          bw[nt] = *reinterpret_cast<const bf16x8*>(
              smem + L_W1 + (((nc * 4 + nt) * 4 + ks) << 10) + lane * 16);
        __builtin_amdgcn_s_setprio(1);
        #pragma unroll
        for (int nt = 0; nt < 4; ++nt) {
          acc1[0][nt] = __builtin_amdgcn_mfma_f32_16x16x32_bf16(bw[nt], af[0][ks], acc1[0][nt], 0, 0, 0);
          acc1[1][nt] = __builtin_amdgcn_mfma_f32_16x16x32_bf16(bw[nt], af[1][ks], acc1[1][nt], 0, 0, 0);
        }
        __builtin_amdgcn_s_setprio(0);
      }
      #pragma unroll
      for (int nt = 0; nt < 4; ++nt) {
        const f32x4 b1q = *reinterpret_cast<const f32x4*>(smB1 + nc * 64 + nt * 16 + 4 * g);
        #pragma unroll
        for (int mt = 0; mt < 2; ++mt) {
          u32x2 w;
          w[0] = packbf2(fmaxf(acc1[mt][nt][0] + b1q[0], 0.f),
                         fmaxf(acc1[mt][nt][1] + b1q[1], 0.f));
          w[1] = packbf2(fmaxf(acc1[mt][nt][2] + b1q[2], 0.f),
                         fmaxf(acc1[mt][nt][3] + b1q[3], 0.f));
          *reinterpret_cast<u32x2*>(Hb + (mt * 16 + q) * 72 + nt * 16 + 4 * g) = w;
        }
      }
      #pragma unroll
      for (int ks2 = 0; ks2 < 2; ++ks2) {
        bf16x8 bh[2];
        #pragma unroll
        for (int mt = 0; mt < 2; ++mt)
          bh[mt] = *reinterpret_cast<const bf16x8*>(Hb + (mt * 16 + q) * 72 + ks2 * 32 + g * 8);
        __builtin_amdgcn_s_setprio(1);
        #pragma unroll
        for (int nt2 = 0; nt2 < 4; ++nt2) {
          acc2[0][nt2] = __builtin_amdgcn_mfma_f32_16x16x32_bf16(bw2f[ks2][nt2], bh[0], acc2[0][nt2], 0, 0, 0);
          acc2[1][nt2] = __builtin_amdgcn_mfma_f32_16x16x32_bf16(bw2f[ks2][nt2], bh[1], acc2[1][nt2], 0, 0, 0);
        }
        __builtin_amdgcn_s_setprio(0);
      }
    }

    if (it < 3) LOADX(b0 + it + 1);

    __hip_bfloat16* Sl = Hb;
    #pragma unroll
    for (int nt2 = 0; nt2 < 4; ++nt2) {
      const f32x4 bcq = *reinterpret_cast<const f32x4*>(smBC + nt2 * 16 + 4 * g);
      #pragma unroll
      for (int mt = 0; mt < 2; ++mt) {
        u32x2 w;
        w[0] = packbf2(acc2[mt][nt2][0] + bcq[0], acc2[mt][nt2][1] + bcq[1]);
        w[1] = packbf2(acc2[mt][nt2][2] + bcq[2], acc2[mt][nt2][3] + bcq[3]);
        *reinterpret_cast<u32x2*>(Sl + (mt * 16 + q) * 68 + nt2 * 16 + 4 * g) = w;
      }
    }

    {
      __hip_bfloat16* sigc = reinterpret_cast<__hip_bfloat16*>(
          smem + ((it & 1) ? L_SGB : L_SGA)) + c * 1064;
      #pragma unroll
      for (int w = 0; w < 5; ++w) {
        const int u = w * 64 + lane;
        if (u < 264) {
          const int p = 4 * u, t = p >> 5, j = p & 31;
          u32x2 r1 = {0u, 0u}, r2 = {0u, 0u};
          if (t < 32) r1 = *reinterpret_cast<const u32x2*>(Sl + t * 68 + j);
          if (t > 0)  r2 = *reinterpret_cast<const u32x2*>(Sl + (t - 1) * 68 + j + 32);
          const float nrm = (t == 0 || t == 32) ? 1.f : 0.5f;
          u32x2 wv;
          wv[0] = packbf2(nrm * (lo16f(r1[0]) + lo16f(r2[0])),
                          nrm * (hi16f(r1[0]) + hi16f(r2[0])));
          wv[1] = packbf2(nrm * (lo16f(r1[1]) + lo16f(r2[1])),
                          nrm * (hi16f(r1[1]) + hi16f(r2[1])));
          *reinterpret_cast<u32x2*>(sigc + p) = wv;
        }
      }
    }

    if (it & 1) {
      BAR_LDS();
      const float bconv = smWV[24];
      #pragma unroll 1
      for (int rr = 0; rr < 2; ++rr) {
        const int u = tid + rr * 512;
        if (u < 528) {
          const int half = (u >= 264) ? 1 : 0;
          const __hip_bfloat16* sg = reinterpret_cast<const __hip_bfloat16*>(
              smem + (half ? L_SGB : L_SGA));
          const int p0 = (u - half * 264) * 4;
          f32x4 acc = {bconv, bconv, bconv, bconv};
          #pragma unroll
          for (int cc = 0; cc < 8; ++cc) {
            const __hip_bfloat16* row = sg + cc * 1064;
            const u32 wm = (p0 > 0) ? *reinterpret_cast<const u32*>(row + p0 - 2) : 0u;
            const u32x2 wc = *reinterpret_cast<const u32x2*>(row + p0);
            const u32 wr = *reinterpret_cast<const u32*>(row + p0 + 4);
            const float l  = hi16f(wm);
            const float a0 = lo16f(wc[0]), a1 = hi16f(wc[0]);
            const float a2 = lo16f(wc[1]), a3 = hi16f(wc[1]);
            const float r  = lo16f(wr);
            const float w0 = smWV[cc * 3], w1 = smWV[cc * 3 + 1], w2 = smWV[cc * 3 + 2];
            acc[0] = fmaf(w0, l,  fmaf(w1, a0, fmaf(w2, a1, acc[0])));
            acc[1] = fmaf(w0, a0, fmaf(w1, a1, fmaf(w2, a2, acc[1])));
            acc[2] = fmaf(w0, a1, fmaf(w1, a2, fmaf(w2, a3, acc[2])));
            acc[3] = fmaf(w0, a2, fmaf(w1, a3, fmaf(w2, r,  acc[3])));
          }
          *reinterpret_cast<f32x4*>(
              Out + (size_t)(b0 + it - 1 + half) * 1056 + p0) = acc;
        }
      }
      if (it != 3) BAR_LDS();
    }
  }
  #undef LOADX
}

extern "C" void kernel_launch(void* const* d_in, const int* in_sizes, int n_in,
                              void* d_out, int out_size, void* d_ws, size_t ws_size,
                              hipStream_t stream) {
  const float* X    = (const float*)d_in[0];
  const float* W1   = (const float*)d_in[1];
  const float* b1   = (const float*)d_in[2];
  const float* W2   = (const float*)d_in[3];
  const float* b2   = (const float*)d_in[4];
  const float* Winv = (const float*)d_in[5];
  const float* binv = (const float*)d_in[6];
  const float* Wcv  = (const float*)d_in[7];
  const float* bcv  = (const float*)d_in[8];

  __hip_bfloat16* W1pre = (__hip_bfloat16*)d_ws;                     // 65536 B
  __hip_bfloat16* Wcpre = (__hip_bfloat16*)((char*)d_ws + 65536);    // 32768 B
  float*          bcp   = (float*)((char*)d_ws + 98304);             // 256 B
  __hip_bfloat16* Sig   = (__hip_bfloat16*)((char*)d_ws + 131072);   // 17301504 B
  const size_t need = 131072 + (size_t)1024 * 8 * 1056 * 2;

  k_precomp<<<64, 256, 0, stream>>>(W1, W2, b2, Winv, binv, Wcpre, W1pre, bcp);
  if (ws_size >= need) {
    k_gemm_s3<<<256, 768, 0, stream>>>(X, W1pre, b1, Wcpre, bcp, Sig);
    k_conv<<<1024, 256, 0, stream>>>(Sig, Wcv, bcv, (float*)d_out);
  } else {
    k_gemm_fused<<<256, 512, LDS_SZ, stream>>>(X, W1, b1, Wcpre, bcp, Wcv, bcv,
                                               (float*)d_out);
  }
}

// Round 7
// 72.587 us; speedup vs baseline: 1.4117x; 1.0681x over previous
//
#include <hip/hip_runtime.h>
#include <hip/hip_bf16.h>

// Decoder: B=1024, C=8, T=32, E=128, H=256, SEG=64, STEP=32, SIG=1056. f32 I/O.
// Wc = Winv@W2 (64x256), bc = Winv@b2+binv. Per (b,c):
//   Hm = relu(X W1^T + b1); S = Hm Wc^T + bc; sig = overlap-add(S)/counter;
//   out[b] = conv1d_{C->1,k=3,pad1}(sig) + bconv.
// R27: BARRIER-FREE GEMM. Six rounds established: VGPR alloc is pow2-quantized
//   (m69: waves/SIMD = 8/4/2/1 at <=64/128/256/512 regs); this kernel's ~176
//   unified footprint quantizes to 256 -> 2 waves/SIMD is a HW ceiling; every
//   squeeze attempt spilled ~100MB scratch. So occupancy is fixed; the lever
//   is latency hiding BETWEEN the 2 waves/SIMD. R23's 6 in-loop barriers
//   (needed only for the cross-channel conv) lockstep all 8 waves -> both
//   waves/SIMD stall on the same LDS round-trips simultaneously. This round:
//   conv split out (R24-proven Sig->ws + k_conv); fused GEMM keeps the exact
//   R23 schedule but with ZERO in-loop barriers -> waves drift anti-phase
//   and hide each other's H->bh / S->gather LDS latencies.
//   Fallback: R23 fused kernel (proven 59.1us) if ws too small for Sig.

typedef __bf16 bf16x8 __attribute__((ext_vector_type(8)));
typedef float  f32x4  __attribute__((ext_vector_type(4)));
typedef unsigned int u32;
typedef u32 u32x2 __attribute__((ext_vector_type(2)));

// ---- fused-kernel LDS map (fallback path) ----
#define L_W1   0        // 65536 B  W1 frag layout
#define L_HS   65536    // 36864 B  8 waves x [32][72] bf16 H; S alias [32][68]
#define L_SGA  102400   // 17024 B  sigA bf16 [8][1064] (pads zeroed)
#define L_SGB  119424   // 17024 B  sigB bf16 [8][1064]
#define L_B1   136448   // 1024 B
#define L_BC   137472   // 256 B
#define L_WV   137728   // 128 B
#define LDS_SZ 137856

// ---- R27 barrier-free GEMM LDS map ----
#define M_W1   0        // 65536 B  W1 frag layout
#define M_HS   65536    // 36864 B  8 waves x [32][72] bf16 H; S alias [32][68]
#define M_B1   102400   // 1024 B
#define M_BC   103424   // 256 B
#define M_SZ   103680

// LDS-only barrier: waves' DS writes visible, global loads stay in flight.
#define BAR_LDS() do {                                              \
    __builtin_amdgcn_sched_barrier(0);                              \
    asm volatile("s_waitcnt lgkmcnt(0)" ::: "memory");              \
    __builtin_amdgcn_s_barrier();                                   \
    __builtin_amdgcn_sched_barrier(0);                              \
  } while (0)

static __device__ __forceinline__ bf16x8 cvt8(f32x4 a, f32x4 b) {
  bf16x8 r;
  r[0] = (__bf16)a[0]; r[1] = (__bf16)a[1]; r[2] = (__bf16)a[2]; r[3] = (__bf16)a[3];
  r[4] = (__bf16)b[0]; r[5] = (__bf16)b[1]; r[6] = (__bf16)b[2]; r[7] = (__bf16)b[3];
  return r;
}
static __device__ __forceinline__ u32 packbf2(float a, float b) {
  union { __hip_bfloat16 h; unsigned short s; } ua, ub;
  ua.h = __float2bfloat16(a); ub.h = __float2bfloat16(b);
  return (u32)ua.s | ((u32)ub.s << 16);
}
static __device__ __forceinline__ float lo16f(u32 w) { return __uint_as_float(w << 16); }
static __device__ __forceinline__ float hi16f(u32 w) { return __uint_as_float(w & 0xffff0000u); }

// ---- prep: Wc = Winv@W2 frag layout; bc = Winv@b2 + binv (proven) ----------
__global__ __launch_bounds__(256) void k_precomp(
    const float* __restrict__ W2, const float* __restrict__ b2,
    const float* __restrict__ Winv, const float* __restrict__ binv,
    __hip_bfloat16* __restrict__ Wcpre, float* __restrict__ bc) {
  __shared__ float wrow[128];
  const int s = blockIdx.x, h = threadIdx.x;
  if (h < 128) wrow[h] = Winv[s * 128 + h];
  __syncthreads();
  float acc = 0.f;
  #pragma unroll 8
  for (int e = 0; e < 128; ++e) acc = fmaf(wrow[e], W2[e * 256 + h], acc);
  const int nc = h >> 6, ks2 = (h >> 5) & 1, g = (h >> 3) & 3, j = h & 7;
  const int nt2 = s >> 4, q = s & 15;
  Wcpre[((((nc * 2 + ks2) * 4 + nt2) * 4 + g) * 16 + q) * 8 + j] = __float2bfloat16(acc);
  if (h == 0) {
    float a = binv[s];
    for (int e = 0; e < 128; ++e) a = fmaf(wrow[e], b2[e], a);
    bc[s] = a;
  }
}

// ---- R27 kernel A: exact R23 GEMM schedule, zero in-loop barriers ---------
__global__ __launch_bounds__(512)
__attribute__((amdgpu_waves_per_eu(2, 2)))
void k_gemm_f2(const float* __restrict__ X,      // (1024,8,32,128)
               const float* __restrict__ W1,     // (256,128) raw f32
               const float* __restrict__ b1,     // (256)
               const __hip_bfloat16* __restrict__ Wcpre,   // frag layout, L2
               const float* __restrict__ bcp,    // (64)
               __hip_bfloat16* __restrict__ Sig) // (1024,8,1056) bf16
{
  __shared__ __align__(16) char smem[M_SZ];
  const int tid = threadIdx.x;
  const int wave = tid >> 6, lane = tid & 63;
  const int q = lane & 15, g = lane >> 4;
  const int c = wave;
  const int b0 = blockIdx.x * 4;

  f32x4 xa[16];
  #define LOADX(bb) do {                                                        \
    _Pragma("unroll")                                                           \
    for (int _mt = 0; _mt < 2; ++_mt) {                                         \
      const float* _s = X + ((size_t)((bb) * 8 + c)) * 4096                     \
                          + (_mt * 16 + q) * 128 + g * 8;                       \
      _Pragma("unroll")                                                         \
      for (int _ks = 0; _ks < 4; ++_ks) {                                       \
        xa[(_mt * 4 + _ks) * 2 + 0] = *reinterpret_cast<const f32x4*>(_s + _ks * 32);     \
        xa[(_mt * 4 + _ks) * 2 + 1] = *reinterpret_cast<const f32x4*>(_s + _ks * 32 + 4); \
      } } } while (0)

  // issue iter-0 X loads FIRST; they fly under W1 staging + barrier
  LOADX(b0);

  // ---- stage W1 frags from RAW f32 W1; biases ----
  #pragma unroll
  for (int i = 0; i < 8; ++i) {
    const int p8 = tid + i * 512;
    const int fq = p8 & 15, fg = (p8 >> 4) & 3, fks = (p8 >> 6) & 3;
    const int fnt = (p8 >> 8) & 3, fnc = (p8 >> 10) & 3;
    const float* src = W1 + (fnc * 64 + fnt * 16 + fq) * 128 + fks * 32 + fg * 8;
    *reinterpret_cast<bf16x8*>(smem + M_W1 + p8 * 16) =
        cvt8(*reinterpret_cast<const f32x4*>(src),
             *reinterpret_cast<const f32x4*>(src + 4));
  }
  if (tid < 256)               ((float*)(smem + M_B1))[tid]       = b1[tid];
  if (tid >= 256 && tid < 320) ((float*)(smem + M_BC))[tid - 256] = bcp[tid - 256];
  BAR_LDS();   // the ONLY barrier: W1/bias visibility; xa loads stay in flight

  __hip_bfloat16* Hb = reinterpret_cast<__hip_bfloat16*>(smem + M_HS) + wave * 2304;
  const float* smB1 = (const float*)(smem + M_B1);
  const float* smBC = (const float*)(smem + M_BC);

  #pragma unroll 1
  for (int it = 0; it < 4; ++it) {
    // consume prefetched X -> bf16 frags
    bf16x8 af[2][4];
    #pragma unroll
    for (int f = 0; f < 8; ++f) af[f >> 2][f & 3] = cvt8(xa[2 * f], xa[2 * f + 1]);

    f32x4 acc2[2][4] = {};   // S^T frag: col t = mt*16+q, row s = nt2*16+4g+i

    #pragma unroll 1         // block cross-chunk load hoisting (reg pressure)
    for (int nc = 0; nc < 4; ++nc) {
      // prefetch ALL GEMM2 B-frags for this chunk; GEMM1 covers their L2 latency
      bf16x8 bw2f[2][4];
      #pragma unroll
      for (int ks2 = 0; ks2 < 2; ++ks2)
        #pragma unroll
        for (int nt2 = 0; nt2 < 4; ++nt2)
          bw2f[ks2][nt2] = *reinterpret_cast<const bf16x8*>(
              Wcpre + ((nc * 2 + ks2) * 4 + nt2) * 512 + lane * 8);

      // GEMM1 chunk (swapped): D = W1tile @ X^T -> col=t=q, row=h=4g+i
      f32x4 acc1[2][4] = {};
      #pragma unroll
      for (int ks = 0; ks < 4; ++ks) {
        bf16x8 bw[4];
        #pragma unroll
        for (int nt = 0; nt < 4; ++nt)
          bw[nt] = *reinterpret_cast<const bf16x8*>(
              smem + M_W1 + (((nc * 4 + nt) * 4 + ks) << 10) + lane * 16);
        __builtin_amdgcn_s_setprio(1);
        #pragma unroll
        for (int nt = 0; nt < 4; ++nt) {
          acc1[0][nt] = __builtin_amdgcn_mfma_f32_16x16x32_bf16(bw[nt], af[0][ks], acc1[0][nt], 0, 0, 0);
          acc1[1][nt] = __builtin_amdgcn_mfma_f32_16x16x32_bf16(bw[nt], af[1][ks], acc1[1][nt], 0, 0, 0);
        }
        __builtin_amdgcn_s_setprio(0);
      }
      // +b1, relu -> H chunk [32 t][72 h'], packed b64 writes
      #pragma unroll
      for (int nt = 0; nt < 4; ++nt) {
        const f32x4 b1q = *reinterpret_cast<const f32x4*>(smB1 + nc * 64 + nt * 16 + 4 * g);
        #pragma unroll
        for (int mt = 0; mt < 2; ++mt) {
          u32x2 w;
          w[0] = packbf2(fmaxf(acc1[mt][nt][0] + b1q[0], 0.f),
                         fmaxf(acc1[mt][nt][1] + b1q[1], 0.f));
          w[1] = packbf2(fmaxf(acc1[mt][nt][2] + b1q[2], 0.f),
                         fmaxf(acc1[mt][nt][3] + b1q[3], 0.f));
          *reinterpret_cast<u32x2*>(Hb + (mt * 16 + q) * 72 + nt * 16 + 4 * g) = w;
        }
      }
      // GEMM2 partial (swapped): D = Wc @ H^T -> col=t=q, row=s=4g+i
      #pragma unroll
      for (int ks2 = 0; ks2 < 2; ++ks2) {
        bf16x8 bh[2];
        #pragma unroll
        for (int mt = 0; mt < 2; ++mt)
          bh[mt] = *reinterpret_cast<const bf16x8*>(Hb + (mt * 16 + q) * 72 + ks2 * 32 + g * 8);
        __builtin_amdgcn_s_setprio(1);
        #pragma unroll
        for (int nt2 = 0; nt2 < 4; ++nt2) {
          acc2[0][nt2] = __builtin_amdgcn_mfma_f32_16x16x32_bf16(bw2f[ks2][nt2], bh[0], acc2[0][nt2], 0, 0, 0);
          acc2[1][nt2] = __builtin_amdgcn_mfma_f32_16x16x32_bf16(bw2f[ks2][nt2], bh[1], acc2[1][nt2], 0, 0, 0);
        }
        __builtin_amdgcn_s_setprio(0);
      }
    }

    // issue next batch's X loads AFTER all Wcpre loads of this iteration:
    // vmcnt retires in order, so fragment waits never drain the X prefetch.
    if (it < 3) LOADX(b0 + it + 1);

    // per-wave: S -> own H region [32 t][68 s] (packed b64)
    __hip_bfloat16* Sl = Hb;
    #pragma unroll
    for (int nt2 = 0; nt2 < 4; ++nt2) {
      const f32x4 bcq = *reinterpret_cast<const f32x4*>(smBC + nt2 * 16 + 4 * g);
      #pragma unroll
      for (int mt = 0; mt < 2; ++mt) {
        u32x2 w;
        w[0] = packbf2(acc2[mt][nt2][0] + bcq[0], acc2[mt][nt2][1] + bcq[1]);
        w[1] = packbf2(acc2[mt][nt2][2] + bcq[2], acc2[mt][nt2][3] + bcq[3]);
        *reinterpret_cast<u32x2*>(Sl + (mt * 16 + q) * 68 + nt2 * 16 + 4 * g) = w;
      }
    }

    // overlap-add gather + normalize -> GLOBAL sig[b0+it][c][0..1055], 4/lane
    // (own-wave LDS reads only -> compiler lgkmcnt suffices; NO barrier)
    {
      __hip_bfloat16* sigc = Sig + ((size_t)(b0 + it) * 8 + c) * 1056;
      #pragma unroll
      for (int w = 0; w < 5; ++w) {
        const int u = w * 64 + lane;
        if (u < 264) {
          const int p = 4 * u, t = p >> 5, j = p & 31;
          u32x2 r1 = {0u, 0u}, r2 = {0u, 0u};
          if (t < 32) r1 = *reinterpret_cast<const u32x2*>(Sl + t * 68 + j);
          if (t > 0)  r2 = *reinterpret_cast<const u32x2*>(Sl + (t - 1) * 68 + j + 32);
          const float nrm = (t == 0 || t == 32) ? 1.f : 0.5f;
          u32x2 wv;
          wv[0] = packbf2(nrm * (lo16f(r1[0]) + lo16f(r2[0])),
                          nrm * (hi16f(r1[0]) + hi16f(r2[0])));
          wv[1] = packbf2(nrm * (lo16f(r1[1]) + lo16f(r2[1])),
                          nrm * (hi16f(r1[1]) + hi16f(r2[1])));
          *reinterpret_cast<u32x2*>(sigc + p) = wv;
        }
      }
    }
  }
  #undef LOADX
}

// ---- kernel B: conv1d C->1, k=3, pad1 over sig; one block per batch -------
__global__ __launch_bounds__(256)
void k_conv(const __hip_bfloat16* __restrict__ Sig,   // (1024,8,1056) bf16
            const float* __restrict__ Wcv, const float* __restrict__ bcv,
            float* __restrict__ Out) {                // (1024,1056) f32
  __shared__ float wv[25];
  if (threadIdx.x < 24) wv[threadIdx.x] = Wcv[threadIdx.x];
  if (threadIdx.x == 24) wv[24] = bcv[0];
  __syncthreads();
  const int b = blockIdx.x;
  const float bconv = wv[24];
  #pragma unroll 1
  for (int rr = 0; rr < 2; ++rr) {
    const int u = threadIdx.x + rr * 256;
    if (u < 264) {
      const int p0 = 4 * u;
      f32x4 acc = {bconv, bconv, bconv, bconv};
      #pragma unroll
      for (int cc = 0; cc < 8; ++cc) {
        const __hip_bfloat16* row = Sig + (size_t)(b * 8 + cc) * 1056;
        const u32 wm = (p0 > 0) ? *reinterpret_cast<const u32*>(row + p0 - 2) : 0u;
        const u32x2 wc = *reinterpret_cast<const u32x2*>(row + p0);
        const u32 wr = (p0 + 4 < 1056) ? *reinterpret_cast<const u32*>(row + p0 + 4) : 0u;
        const float l  = hi16f(wm);
        const float a0 = lo16f(wc[0]), a1 = hi16f(wc[0]);
        const float a2 = lo16f(wc[1]), a3 = hi16f(wc[1]);
        const float r  = lo16f(wr);
        const float w0 = wv[cc * 3], w1 = wv[cc * 3 + 1], w2 = wv[cc * 3 + 2];
        acc[0] = fmaf(w0, l,  fmaf(w1, a0, fmaf(w2, a1, acc[0])));
        acc[1] = fmaf(w0, a0, fmaf(w1, a1, fmaf(w2, a2, acc[1])));
        acc[2] = fmaf(w0, a1, fmaf(w1, a2, fmaf(w2, a3, acc[2])));
        acc[3] = fmaf(w0, a2, fmaf(w1, a3, fmaf(w2, r,  acc[3])));
      }
      *reinterpret_cast<f32x4*>(Out + (size_t)b * 1056 + p0) = acc;
    }
  }
}

// ---- fallback: R23 fused kernel (proven 59.1us), used if ws too small ------
__global__ __launch_bounds__(512)
__attribute__((amdgpu_waves_per_eu(2, 2)))
void k_gemm_fused(const float* __restrict__ X,
                  const float* __restrict__ W1,
                  const float* __restrict__ b1,
                  const __hip_bfloat16* __restrict__ Wcpre,
                  const float* __restrict__ bcp,
                  const float* __restrict__ Wcv,
                  const float* __restrict__ bcv,
                  float* __restrict__ Out) {
  extern __shared__ __align__(16) char smem[];
  const int tid = threadIdx.x;
  const int wave = tid >> 6, lane = tid & 63;
  const int q = lane & 15, g = lane >> 4;
  const int c = wave;
  const int b0 = blockIdx.x * 4;

  f32x4 xa[16];
  #define LOADX(bb) do {                                                        \
    _Pragma("unroll")                                                           \
    for (int _mt = 0; _mt < 2; ++_mt) {                                         \
      const float* _s = X + ((size_t)((bb) * 8 + c)) * 4096                     \
                          + (_mt * 16 + q) * 128 + g * 8;                       \
      _Pragma("unroll")                                                         \
      for (int _ks = 0; _ks < 4; ++_ks) {                                       \
        xa[(_mt * 4 + _ks) * 2 + 0] = *reinterpret_cast<const f32x4*>(_s + _ks * 32);     \
        xa[(_mt * 4 + _ks) * 2 + 1] = *reinterpret_cast<const f32x4*>(_s + _ks * 32 + 4); \
      } } } while (0)

  LOADX(b0);

  #pragma unroll
  for (int i = 0; i < 8; ++i) {
    const int p8 = tid + i * 512;
    const int fq = p8 & 15, fg = (p8 >> 4) & 3, fks = (p8 >> 6) & 3;
    const int fnt = (p8 >> 8) & 3, fnc = (p8 >> 10) & 3;
    const float* src = W1 + (fnc * 64 + fnt * 16 + fq) * 128 + fks * 32 + fg * 8;
    *reinterpret_cast<bf16x8*>(smem + L_W1 + p8 * 16) =
        cvt8(*reinterpret_cast<const f32x4*>(src),
             *reinterpret_cast<const f32x4*>(src + 4));
  }
  {
    if (tid < 256)               ((float*)(smem + L_B1))[tid]       = b1[tid];
    if (tid >= 256 && tid < 320) ((float*)(smem + L_BC))[tid - 256] = bcp[tid - 256];
    if (tid >= 320 && tid < 344) ((float*)(smem + L_WV))[tid - 320] = Wcv[tid - 320];
    if (tid == 344)              ((float*)(smem + L_WV))[24]        = bcv[0];
    if (tid >= 384 && tid < 448) {
      const int t = tid - 384, buf = t >> 5, cc = (t & 31) >> 2, k = t & 3;
      *reinterpret_cast<u32*>(
          reinterpret_cast<__hip_bfloat16*>(smem + (buf ? L_SGB : L_SGA))
          + cc * 1064 + 1056 + 2 * k) = 0u;
    }
  }
  BAR_LDS();

  __hip_bfloat16* Hb = reinterpret_cast<__hip_bfloat16*>(smem + L_HS) + wave * 2304;
  const float* smB1 = (const float*)(smem + L_B1);
  const float* smBC = (const float*)(smem + L_BC);
  const float* smWV = (const float*)(smem + L_WV);

  #pragma unroll 1
  for (int it = 0; it < 4; ++it) {
    bf16x8 af[2][4];
    #pragma unroll
    for (int f = 0; f < 8; ++f) af[f >> 2][f & 3] = cvt8(xa[2 * f], xa[2 * f + 1]);

    f32x4 acc2[2][4] = {};

    #pragma unroll 1
    for (int nc = 0; nc < 4; ++nc) {
      bf16x8 bw2f[2][4];
      #pragma unroll
      for (int ks2 = 0; ks2 < 2; ++ks2)
        #pragma unroll
        for (int nt2 = 0; nt2 < 4; ++nt2)
          bw2f[ks2][nt2] = *reinterpret_cast<const bf16x8*>(
              Wcpre + ((nc * 2 + ks2) * 4 + nt2) * 512 + lane * 8);

      f32x4 acc1[2][4] = {};
      #pragma unroll
      for (int ks = 0; ks < 4; ++ks) {
        bf16x8 bw[4];
        #pragma unroll
        for (int nt = 0; nt < 4; ++nt)
          bw[nt] = *reinterpret_cast<const bf16x8*>(
              smem + L_W1 + (((nc * 4 + nt) * 4 + ks) << 10) + lane * 16);
        __builtin_amdgcn_s_setprio(1);
        #pragma unroll
        for (int nt = 0; nt < 4; ++nt) {
          acc1[0][nt] = __builtin_amdgcn_mfma_f32_16x16x32_bf16(bw[nt], af[0][ks], acc1[0][nt], 0, 0, 0);
          acc1[1][nt] = __builtin_amdgcn_mfma_f32_16x16x32_bf16(bw[nt], af[1][ks], acc1[1][nt], 0, 0, 0);
        }
        __builtin_amdgcn_s_setprio(0);
      }
      #pragma unroll
      for (int nt = 0; nt < 4; ++nt) {
        const f32x4 b1q = *reinterpret_cast<const f32x4*>(smB1 + nc * 64 + nt * 16 + 4 * g);
        #pragma unroll
        for (int mt = 0; mt < 2; ++mt) {
          u32x2 w;
          w[0] = packbf2(fmaxf(acc1[mt][nt][0] + b1q[0], 0.f),
                         fmaxf(acc1[mt][nt][1] + b1q[1], 0.f));
          w[1] = packbf2(fmaxf(acc1[mt][nt][2] + b1q[2], 0.f),
                         fmaxf(acc1[mt][nt][3] + b1q[3], 0.f));
          *reinterpret_cast<u32x2*>(Hb + (mt * 16 + q) * 72 + nt * 16 + 4 * g) = w;
        }
      }
      #pragma unroll
      for (int ks2 = 0; ks2 < 2; ++ks2) {
        bf16x8 bh[2];
        #pragma unroll
        for (int mt = 0; mt < 2; ++mt)
          bh[mt] = *reinterpret_cast<const bf16x8*>(Hb + (mt * 16 + q) * 72 + ks2 * 32 + g * 8);
        __builtin_amdgcn_s_setprio(1);
        #pragma unroll
        for (int nt2 = 0; nt2 < 4; ++nt2) {
          acc2[0][nt2] = __builtin_amdgcn_mfma_f32_16x16x32_bf16(bw2f[ks2][nt2], bh[0], acc2[0][nt2], 0, 0, 0);
          acc2[1][nt2] = __builtin_amdgcn_mfma_f32_16x16x32_bf16(bw2f[ks2][nt2], bh[1], acc2[1][nt2], 0, 0, 0);
        }
        __builtin_amdgcn_s_setprio(0);
      }
    }

    if (it < 3) LOADX(b0 + it + 1);

    __hip_bfloat16* Sl = Hb;
    #pragma unroll
    for (int nt2 = 0; nt2 < 4; ++nt2) {
      const f32x4 bcq = *reinterpret_cast<const f32x4*>(smBC + nt2 * 16 + 4 * g);
      #pragma unroll
      for (int mt = 0; mt < 2; ++mt) {
        u32x2 w;
        w[0] = packbf2(acc2[mt][nt2][0] + bcq[0], acc2[mt][nt2][1] + bcq[1]);
        w[1] = packbf2(acc2[mt][nt2][2] + bcq[2], acc2[mt][nt2][3] + bcq[3]);
        *reinterpret_cast<u32x2*>(Sl + (mt * 16 + q) * 68 + nt2 * 16 + 4 * g) = w;
      }
    }

    {
      __hip_bfloat16* sigc = reinterpret_cast<__hip_bfloat16*>(
          smem + ((it & 1) ? L_SGB : L_SGA)) + c * 1064;
      #pragma unroll
      for (int w = 0; w < 5; ++w) {
        const int u = w * 64 + lane;
        if (u < 264) {
          const int p = 4 * u, t = p >> 5, j = p & 31;
          u32x2 r1 = {0u, 0u}, r2 = {0u, 0u};
          if (t < 32) r1 = *reinterpret_cast<const u32x2*>(Sl + t * 68 + j);
          if (t > 0)  r2 = *reinterpret_cast<const u32x2*>(Sl + (t - 1) * 68 + j + 32);
          const float nrm = (t == 0 || t == 32) ? 1.f : 0.5f;
          u32x2 wv;
          wv[0] = packbf2(nrm * (lo16f(r1[0]) + lo16f(r2[0])),
                          nrm * (hi16f(r1[0]) + hi16f(r2[0])));
          wv[1] = packbf2(nrm * (lo16f(r1[1]) + lo16f(r2[1])),
                          nrm * (hi16f(r1[1]) + hi16f(r2[1])));
          *reinterpret_cast<u32x2*>(sigc + p) = wv;
        }
      }
    }

    if (it & 1) {
      BAR_LDS();
      const float bconv = smWV[24];
      #pragma unroll 1
      for (int rr = 0; rr < 2; ++rr) {
        const int u = tid + rr * 512;
        if (u < 528) {
          const int half = (u >= 264) ? 1 : 0;
          const __hip_bfloat16* sg = reinterpret_cast<const __hip_bfloat16*>(
              smem + (half ? L_SGB : L_SGA));
          const int p0 = (u - half * 264) * 4;
          f32x4 acc = {bconv, bconv, bconv, bconv};
          #pragma unroll
          for (int cc = 0; cc < 8; ++cc) {
            const __hip_bfloat16* row = sg + cc * 1064;
            const u32 wm = (p0 > 0) ? *reinterpret_cast<const u32*>(row + p0 - 2) : 0u;
            const u32x2 wc = *reinterpret_cast<const u32x2*>(row + p0);
            const u32 wr = *reinterpret_cast<const u32*>(row + p0 + 4);
            const float l  = hi16f(wm);
            const float a0 = lo16f(wc[0]), a1 = hi16f(wc[0]);
            const float a2 = lo16f(wc[1]), a3 = hi16f(wc[1]);
            const float r  = lo16f(wr);
            const float w0 = smWV[cc * 3], w1 = smWV[cc * 3 + 1], w2 = smWV[cc * 3 + 2];
            acc[0] = fmaf(w0, l,  fmaf(w1, a0, fmaf(w2, a1, acc[0])));
            acc[1] = fmaf(w0, a0, fmaf(w1, a1, fmaf(w2, a2, acc[1])));
            acc[2] = fmaf(w0, a1, fmaf(w1, a2, fmaf(w2, a3, acc[2])));
            acc[3] = fmaf(w0, a2, fmaf(w1, a3, fmaf(w2, r,  acc[3])));
          }
          *reinterpret_cast<f32x4*>(
              Out + (size_t)(b0 + it - 1 + half) * 1056 + p0) = acc;
        }
      }
      if (it != 3) BAR_LDS();
    }
  }
  #undef LOADX
}

extern "C" void kernel_launch(void* const* d_in, const int* in_sizes, int n_in,
                              void* d_out, int out_size, void* d_ws, size_t ws_size,
                              hipStream_t stream) {
  const float* X    = (const float*)d_in[0];
  const float* W1   = (const float*)d_in[1];
  const float* b1   = (const float*)d_in[2];
  const float* W2   = (const float*)d_in[3];
  const float* b2   = (const float*)d_in[4];
  const float* Winv = (const float*)d_in[5];
  const float* binv = (const float*)d_in[6];
  const float* Wcv  = (const float*)d_in[7];
  const float* bcv  = (const float*)d_in[8];

  __hip_bfloat16* Wcpre = (__hip_bfloat16*)((char*)d_ws + 65536);    // 32768 B
  float*          bcp   = (float*)((char*)d_ws + 98304);             // 256 B
  __hip_bfloat16* Sig   = (__hip_bfloat16*)((char*)d_ws + 131072);   // 17301504 B
  const size_t need = 131072 + (size_t)1024 * 8 * 1056 * 2;

  k_precomp<<<64, 256, 0, stream>>>(W2, b2, Winv, binv, Wcpre, bcp);
  if (ws_size >= need) {
    k_gemm_f2<<<256, 512, 0, stream>>>(X, W1, b1, Wcpre, bcp, Sig);
    k_conv<<<1024, 256, 0, stream>>>(Sig, Wcv, bcv, (float*)d_out);
  } else {
    k_gemm_fused<<<256, 512, LDS_SZ, stream>>>(X, W1, b1, Wcpre, bcp, Wcv, bcv,
                                               (float*)d_out);
  }
}